// Round 5
// baseline (273.175 us; speedup 1.0000x reference)
//
#include <hip/hip_runtime.h>

#define N_NODES 50000
#define N_EDGES 800000

typedef __attribute__((ext_vector_type(8))) short bf16x8;
typedef __attribute__((ext_vector_type(4))) float f32x4;

// ---------------- workspace layout (bytes) ----------------
#define OFF_BUFB      0UL          // layer-1 output (50000*128 f32)
#define OFF_CNT       25600000UL   // 200,000
#define OFF_CURSOR    25800000UL   // 200,000 (classic path only)
#define OFF_CTR       26000000UL   // 16
#define OFF_ROWSTART  26000016UL   // 200,004 (classic path only)
#define OFF_W         26200032UL   // 360,448 (bf16 hi/lo weight pool), 16B aligned
#define OFF_CSR       26560480UL   // classic: 3.2MB ; padded: 12.8MB
#define PAD_NEEDED    39360480UL   // end of padded CSR

__device__ __forceinline__ unsigned short bf16_rne(float f) {
  unsigned u = __float_as_uint(f);
  unsigned r = (u + 0x7FFFu + ((u >> 16) & 1u)) >> 16;
  return (unsigned short)r;
}

__device__ __forceinline__ int swz(int row, int b) {
  return (row * 256 + b) ^ ((row & 7) << 4);
}

// ---------------- CSR build: padded single-pass ----------------
__global__ __launch_bounds__(256)
void scatter_pad(const int* __restrict__ src, const int* __restrict__ dst,
                 int* __restrict__ cnt, int* __restrict__ csr, int E) {
  int i = blockIdx.x * 256 + threadIdx.x;
  if (i < E) {
    int d = dst[i];
    int pos = atomicAdd(&cnt[d], 1);
    if (pos < 64) csr[(d << 6) + pos] = src[i];
  }
}

// ---------------- CSR build: classic 3-pass (fallback if ws too small) ----------------
__global__ __launch_bounds__(256)
void hist_kernel(const int* __restrict__ dst, int* __restrict__ cnt, int E) {
  int i = blockIdx.x * 256 + threadIdx.x;
  if (i < E) atomicAdd(&cnt[dst[i]], 1);
}

__global__ __launch_bounds__(256)
void blockscan_kernel(const int* __restrict__ cnt, int* __restrict__ row_start,
                      int* __restrict__ counter, int n) {
  __shared__ int wsum[4];
  __shared__ int sbase;
  int i = blockIdx.x * 256 + threadIdx.x;
  int lane = threadIdx.x & 63;
  int wid = threadIdx.x >> 6;
  int v = (i < n) ? cnt[i] : 0;
  int x = v;
  #pragma unroll
  for (int off = 1; off < 64; off <<= 1) {
    int y = __shfl_up(x, off);
    if (lane >= off) x += y;
  }
  if (lane == 63) wsum[wid] = x;
  __syncthreads();
  if (threadIdx.x == 0) {
    int t0 = wsum[0], t1 = wsum[1], t2 = wsum[2], t3 = wsum[3];
    sbase = atomicAdd(counter, t0 + t1 + t2 + t3);
    wsum[0] = 0; wsum[1] = t0; wsum[2] = t0 + t1; wsum[3] = t0 + t1 + t2;
  }
  __syncthreads();
  if (i < n) row_start[i] = sbase + wsum[wid] + (x - v);
}

__global__ __launch_bounds__(256)
void scatter_kernel(const int* __restrict__ src, const int* __restrict__ dst,
                    const int* __restrict__ row_start, int* __restrict__ cursor,
                    int* __restrict__ csr_src, int E) {
  int i = blockIdx.x * 256 + threadIdx.x;
  if (i < E) {
    int d = dst[i];
    int pos = atomicAdd(&cursor[d], 1);
    csr_src[row_start[d] + pos] = src[i];
  }
}

// ---------------- weights -> bf16 hi/lo, [n][k] row-major ----------------
__global__ __launch_bounds__(256)
void wconvert(const float* __restrict__ W1a, const float* __restrict__ W1b,
              const float* __restrict__ W2a, const float* __restrict__ W2b,
              const float* __restrict__ W3a, const float* __restrict__ W3b,
              unsigned short* __restrict__ pool) {
  int i = blockIdx.x * 256 + threadIdx.x;
  const float* src;
  int base, local, msize;
  if (i < 16384)      { src = W1a; base = 0;      local = i;          msize = 16384; }
  else if (i < 32768) { src = W1b; base = 32768;  local = i - 16384;  msize = 16384; }
  else if (i < 49152) { src = W2a; base = 65536;  local = i - 32768;  msize = 16384; }
  else if (i < 65536) { src = W2b; base = 98304;  local = i - 49152;  msize = 16384; }
  else if (i < 81920) { src = W3a; base = 131072; local = i - 65536;  msize = 16384; }
  else if (i < 90112) { src = W3b; base = 163840; local = i - 81920;  msize = 8192;  }
  else return;
  float f = src[local];
  unsigned short hi = bf16_rne(f);
  float fh = __uint_as_float((unsigned)hi << 16);
  unsigned short lo = bf16_rne(f - fh);
  pool[base + local] = hi;
  pool[base + msize + local] = lo;
}

// ---------------- building blocks for the fused kernels ----------------

// gather + self-add, write bf16 hi/lo straight into LDS (row = local node idx)
template <bool PAD>
__device__ __forceinline__ void agg_stage(const float* __restrict__ x,
                                          const int* __restrict__ csr,
                                          const int* __restrict__ row_start,
                                          const int* __restrict__ cnt,
                                          int m0, int w, int lane,
                                          char* ahi, char* alo, int M) {
  const int half = lane >> 5;
  const int c4 = (lane & 31) * 4;
  #pragma unroll 1
  for (int n = 0; n < 16; ++n) {
    int row = w * 16 + n;
    int node = m0 + row;
    f32x4 o = (f32x4){0.f, 0.f, 0.f, 0.f};
    if (node < M) {
      int degt = cnt[node];
      int dloop = PAD ? min(degt, 64) : degt;
      int beg = PAD ? (node << 6) : row_start[node];
      float inv = 1.0f / fmaxf((float)degt, 1.0f);
      f32x4 a8[8];
      #pragma unroll
      for (int j = 0; j < 8; ++j) a8[j] = (f32x4){0.f, 0.f, 0.f, 0.f};
      for (int t = 0; t < dloop; t += 16) {
        int idx[8];
        float mm[8];
        #pragma unroll
        for (int j = 0; j < 8; ++j) {
          int ee = t + 2 * j + half;
          bool ok = ee < dloop;
          idx[j] = ok ? csr[beg + ee] : node;
          mm[j] = ok ? 1.f : 0.f;
        }
        #pragma unroll
        for (int j = 0; j < 8; ++j) {
          f32x4 u = *reinterpret_cast<const f32x4*>(x + (size_t)idx[j] * 128 + c4);
          a8[j][0] = fmaf(mm[j], u[0], a8[j][0]);
          a8[j][1] = fmaf(mm[j], u[1], a8[j][1]);
          a8[j][2] = fmaf(mm[j], u[2], a8[j][2]);
          a8[j][3] = fmaf(mm[j], u[3], a8[j][3]);
        }
      }
      f32x4 s = a8[0];
      #pragma unroll
      for (int j = 1; j < 8; ++j) {
        s[0] += a8[j][0]; s[1] += a8[j][1]; s[2] += a8[j][2]; s[3] += a8[j][3];
      }
      #pragma unroll
      for (int r = 0; r < 4; ++r) s[r] += __shfl_xor(s[r], 32);
      f32x4 xv = *reinterpret_cast<const f32x4*>(x + (size_t)node * 128 + c4);
      #pragma unroll
      for (int r = 0; r < 4; ++r) o[r] = fmaf(s[r], inv, xv[r]);
    }
    if (half == 0) {
      ushort4 hi, lo;
      float fh;
      hi.x = bf16_rne(o[0]); fh = __uint_as_float((unsigned)hi.x << 16); lo.x = bf16_rne(o[0] - fh);
      hi.y = bf16_rne(o[1]); fh = __uint_as_float((unsigned)hi.y << 16); lo.y = bf16_rne(o[1] - fh);
      hi.z = bf16_rne(o[2]); fh = __uint_as_float((unsigned)hi.z << 16); lo.z = bf16_rne(o[2] - fh);
      hi.w = bf16_rne(o[3]); fh = __uint_as_float((unsigned)hi.w << 16); lo.w = bf16_rne(o[3] - fh);
      int bo = swz(row, (lane & 31) * 8);
      *reinterpret_cast<ushort4*>(ahi + bo) = hi;
      *reinterpret_cast<ushort4*>(alo + bo) = lo;
    }
  }
}

template <int NB>
__device__ __forceinline__ void load_bfrag(const unsigned short* __restrict__ Wh,
                                           const unsigned short* __restrict__ Wl,
                                           int w, int lrow, int lg,
                                           bf16x8 (&bh)[NB][4], bf16x8 (&bl)[NB][4]) {
  #pragma unroll
  for (int nb = 0; nb < NB; ++nb) {
    int col = w * (16 * NB) + nb * 16 + lrow;
    #pragma unroll
    for (int kk = 0; kk < 4; ++kk) {
      int idx = col * 128 + kk * 32 + lg * 8;
      bh[nb][kk] = *reinterpret_cast<const bf16x8*>(Wh + idx);
      bl[nb][kk] = *reinterpret_cast<const bf16x8*>(Wl + idx);
    }
  }
}

template <int NB>
__device__ __forceinline__ void gemm_lds(const char* ahi, const char* alo, int lrow, int lg,
                                         const bf16x8 (&bh)[NB][4], const bf16x8 (&bl)[NB][4],
                                         f32x4 (&acc)[4][NB]) {
  #pragma unroll
  for (int i = 0; i < 4; ++i)
    #pragma unroll
    for (int nb = 0; nb < NB; ++nb) acc[i][nb] = (f32x4){0.f, 0.f, 0.f, 0.f};
  #pragma unroll
  for (int i = 0; i < 4; ++i) {
    #pragma unroll
    for (int kk = 0; kk < 4; ++kk) {
      int bo = swz(i * 16 + lrow, kk * 64 + lg * 16);
      bf16x8 ah = *reinterpret_cast<const bf16x8*>(ahi + bo);
      bf16x8 al = *reinterpret_cast<const bf16x8*>(alo + bo);
      #pragma unroll
      for (int nb = 0; nb < NB; ++nb) {
        acc[i][nb] = __builtin_amdgcn_mfma_f32_16x16x32_bf16(ah, bh[nb][kk], acc[i][nb], 0, 0, 0);
        acc[i][nb] = __builtin_amdgcn_mfma_f32_16x16x32_bf16(al, bh[nb][kk], acc[i][nb], 0, 0, 0);
        acc[i][nb] = __builtin_amdgcn_mfma_f32_16x16x32_bf16(ah, bl[nb][kk], acc[i][nb], 0, 0, 0);
      }
    }
  }
}

// h = relu(acc + bias) -> LDS bf16 hi/lo (always 128 cols wide, NB=2)
__device__ __forceinline__ void store_h(char* ahi, char* alo, const float* __restrict__ bias,
                                        int w, int lrow, int lg, f32x4 (&acc)[4][2]) {
  #pragma unroll
  for (int i = 0; i < 4; ++i) {
    #pragma unroll
    for (int nb = 0; nb < 2; ++nb) {
      int col = w * 32 + nb * 16 + lrow;
      float b = bias[col];
      #pragma unroll
      for (int r = 0; r < 4; ++r) {
        float v = fmaxf(acc[i][nb][r] + b, 0.f);
        int row = i * 16 + lg * 4 + r;
        unsigned short h = bf16_rne(v);
        float fh = __uint_as_float((unsigned)h << 16);
        unsigned short l2 = bf16_rne(v - fh);
        int bo = swz(row, col * 2);
        *reinterpret_cast<unsigned short*>(ahi + bo) = h;
        *reinterpret_cast<unsigned short*>(alo + bo) = l2;
      }
    }
  }
}

template <int NB, bool RELU>
__device__ __forceinline__ void epilogue(float* __restrict__ Y, const float* __restrict__ bias,
                                         int m0, int w, int lrow, int lg,
                                         f32x4 (&acc)[4][NB], int M) {
  constexpr int NOUT = NB * 64;
  #pragma unroll
  for (int i = 0; i < 4; ++i) {
    #pragma unroll
    for (int nb = 0; nb < NB; ++nb) {
      int col = w * (16 * NB) + nb * 16 + lrow;
      float b = bias[col];
      #pragma unroll
      for (int r = 0; r < 4; ++r) {
        float v = acc[i][nb][r] + b;
        if (RELU) v = fmaxf(v, 0.f);
        int row = m0 + i * 16 + lg * 4 + r;
        if (row < M) Y[(size_t)row * NOUT + col] = v;
      }
    }
  }
}

// ---------------- K1: agg(feat) + mlp1 (2 GEMMs) -> bufB (relu, fp32) ----------------
template <bool PAD>
__global__ __launch_bounds__(256)
void fused_l1(const float* __restrict__ X, const int* __restrict__ csr,
              const int* __restrict__ row_start, const int* __restrict__ cnt,
              const unsigned short* __restrict__ p, const float* __restrict__ b1a,
              const float* __restrict__ b1b, float* __restrict__ Y, int M) {
  __shared__ unsigned short Ahi[64 * 128];
  __shared__ unsigned short Alo[64 * 128];
  char* ahi = (char*)Ahi;
  char* alo = (char*)Alo;
  const int tid = threadIdx.x;
  const int w = tid >> 6, l = tid & 63;
  const int lrow = l & 15, lg = l >> 4;
  const int m0 = blockIdx.x * 64;

  agg_stage<PAD>(X, csr, row_start, cnt, m0, w, l, ahi, alo, M);
  __syncthreads();

  f32x4 acc[4][2];
  {
    bf16x8 bh[2][4], bl[2][4];
    load_bfrag<2>(p + 0, p + 16384, w, lrow, lg, bh, bl);
    gemm_lds<2>(ahi, alo, lrow, lg, bh, bl, acc);
  }
  __syncthreads();
  {
    bf16x8 bh[2][4], bl[2][4];
    load_bfrag<2>(p + 32768, p + 49152, w, lrow, lg, bh, bl);
    store_h(ahi, alo, b1a, w, lrow, lg, acc);
    __syncthreads();
    gemm_lds<2>(ahi, alo, lrow, lg, bh, bl, acc);
  }
  epilogue<2, true>(Y, b1b, m0, w, lrow, lg, acc, M);
}

// ---------------- K2: agg(bufB) + mlp2 (2 GEMMs) + head (2 GEMMs) -> d_out ----------------
template <bool PAD>
__global__ __launch_bounds__(256)
void fused_l2_head(const float* __restrict__ X, const int* __restrict__ csr,
                   const int* __restrict__ row_start, const int* __restrict__ cnt,
                   const unsigned short* __restrict__ p,
                   const float* __restrict__ b2a, const float* __restrict__ b2b,
                   const float* __restrict__ b3a, const float* __restrict__ b3b,
                   float* __restrict__ Y, int M) {
  __shared__ unsigned short Ahi[64 * 128];
  __shared__ unsigned short Alo[64 * 128];
  char* ahi = (char*)Ahi;
  char* alo = (char*)Alo;
  const int tid = threadIdx.x;
  const int w = tid >> 6, l = tid & 63;
  const int lrow = l & 15, lg = l >> 4;
  const int m0 = blockIdx.x * 64;

  agg_stage<PAD>(X, csr, row_start, cnt, m0, w, l, ahi, alo, M);
  __syncthreads();

  f32x4 acc[4][2];
  {
    bf16x8 bh[2][4], bl[2][4];
    load_bfrag<2>(p + 65536, p + 81920, w, lrow, lg, bh, bl);   // W2a
    gemm_lds<2>(ahi, alo, lrow, lg, bh, bl, acc);
  }
  __syncthreads();
  {
    bf16x8 bh[2][4], bl[2][4];
    load_bfrag<2>(p + 98304, p + 114688, w, lrow, lg, bh, bl);  // W2b
    store_h(ahi, alo, b2a, w, lrow, lg, acc);
    __syncthreads();
    gemm_lds<2>(ahi, alo, lrow, lg, bh, bl, acc);
  }
  __syncthreads();
  {
    bf16x8 bh[2][4], bl[2][4];
    load_bfrag<2>(p + 131072, p + 147456, w, lrow, lg, bh, bl); // W3a
    store_h(ahi, alo, b2b, w, lrow, lg, acc);                   // outer relu of layer 2
    __syncthreads();
    gemm_lds<2>(ahi, alo, lrow, lg, bh, bl, acc);
  }
  __syncthreads();
  f32x4 acc1[4][1];
  {
    bf16x8 bh[1][4], bl[1][4];
    load_bfrag<1>(p + 163840, p + 172032, w, lrow, lg, bh, bl); // W3b (64 cols)
    store_h(ahi, alo, b3a, w, lrow, lg, acc);
    __syncthreads();
    gemm_lds<1>(ahi, alo, lrow, lg, bh, bl, acc1);
  }
  epilogue<1, false>(Y, b3b, m0, w, lrow, lg, acc1, M);
}

// ---------------- launch ----------------
extern "C" void kernel_launch(void* const* d_in, const int* in_sizes, int n_in,
                              void* d_out, int out_size, void* d_ws, size_t ws_size,
                              hipStream_t stream) {
  const float* feat = (const float*)d_in[0];
  const int*   esrc = (const int*)d_in[1];
  const int*   edst = (const int*)d_in[2];
  const float* W1a = (const float*)d_in[3];  const float* b1a = (const float*)d_in[4];
  const float* W1b = (const float*)d_in[5];  const float* b1b = (const float*)d_in[6];
  const float* W2a = (const float*)d_in[7];  const float* b2a = (const float*)d_in[8];
  const float* W2b = (const float*)d_in[9];  const float* b2b = (const float*)d_in[10];
  const float* W3a = (const float*)d_in[11]; const float* b3a = (const float*)d_in[12];
  const float* W3b = (const float*)d_in[13]; const float* b3b = (const float*)d_in[14];

  char* ws = (char*)d_ws;
  float* bufB      = (float*)(ws + OFF_BUFB);
  int*   cnt       = (int*)  (ws + OFF_CNT);
  int*   cursor    = (int*)  (ws + OFF_CURSOR);
  int*   ctr       = (int*)  (ws + OFF_CTR);
  int*   row_start = (int*)  (ws + OFF_ROWSTART);
  unsigned short* p = (unsigned short*)(ws + OFF_W);
  int*   csr       = (int*)  (ws + OFF_CSR);

  const bool padded = (ws_size >= PAD_NEEDED);

  hipMemsetAsync(ws + OFF_CNT, 0, 400016, stream);

  if (padded) {
    scatter_pad<<<(N_EDGES + 255) / 256, 256, 0, stream>>>(esrc, edst, cnt, csr, N_EDGES);
  } else {
    hist_kernel<<<(N_EDGES + 255) / 256, 256, 0, stream>>>(edst, cnt, N_EDGES);
    blockscan_kernel<<<(N_NODES + 255) / 256, 256, 0, stream>>>(cnt, row_start, ctr, N_NODES);
    scatter_kernel<<<(N_EDGES + 255) / 256, 256, 0, stream>>>(esrc, edst, row_start, cursor, csr, N_EDGES);
  }
  wconvert<<<(90112 + 255) / 256, 256, 0, stream>>>(W1a, W1b, W2a, W2b, W3a, W3b, p);

  const int GB = (N_NODES + 63) / 64;    // 782

  if (padded) {
    fused_l1<true><<<GB, 256, 0, stream>>>(feat, csr, row_start, cnt, p, b1a, b1b, bufB, N_NODES);
    fused_l2_head<true><<<GB, 256, 0, stream>>>(bufB, csr, row_start, cnt, p,
                                                b2a, b2b, b3a, b3b, (float*)d_out, N_NODES);
  } else {
    fused_l1<false><<<GB, 256, 0, stream>>>(feat, csr, row_start, cnt, p, b1a, b1b, bufB, N_NODES);
    fused_l2_head<false><<<GB, 256, 0, stream>>>(bufB, csr, row_start, cnt, p,
                                                 b2a, b2b, b3a, b3b, (float*)d_out, N_NODES);
  }
}

// Round 6
// 212.431 us; speedup vs baseline: 1.2859x; 1.2859x over previous
//
#include <hip/hip_runtime.h>
#include <hip/hip_fp16.h>

#define N_NODES 50000
#define N_EDGES 800000

typedef __attribute__((ext_vector_type(8))) short bf16x8;
typedef __attribute__((ext_vector_type(4))) float f32x4;

// ---------------- workspace layout (bytes), total 51,760,512 ----------------
#define OFF_BUFA   0UL          // 25,600,000  agg output fp32 [50000][128]
#define OFF_T16    25600000UL   // 12,800,000  fp16 feature table [50000][128]
#define OFF_CNT    38400000UL   //    200,000  degree counts
#define OFF_W      38600064UL   //    360,448  bf16 hi/lo weight pool
#define OFF_CSR    38960512UL   // 12,800,000  padded CSR (64 slots/node)

#define NB_EDGE 3125   // 800000/256
#define NB_W    352    // 90112/256
#define NB_FEAT 6250   // 6,400,000/(256*4)

__device__ __forceinline__ unsigned short bf16_rne(float f) {
  unsigned u = __float_as_uint(f);
  unsigned r = (u + 0x7FFFu + ((u >> 16) & 1u)) >> 16;
  return (unsigned short)r;
}

__device__ __forceinline__ int swz(int row, int b) {
  return (row * 256 + b) ^ ((row & 7) << 4);
}

// ---------------- prep: padded-CSR scatter + weight convert + feat->fp16 ----------------
__global__ __launch_bounds__(256)
void prep_kernel(const int* __restrict__ src, const int* __restrict__ dst,
                 int* __restrict__ cnt, int* __restrict__ csr,
                 const float* __restrict__ W1a, const float* __restrict__ W1b,
                 const float* __restrict__ W2a, const float* __restrict__ W2b,
                 const float* __restrict__ W3a, const float* __restrict__ W3b,
                 unsigned short* __restrict__ pool,
                 const float* __restrict__ feat, __half* __restrict__ t16) {
  const int b = blockIdx.x;
  const int tid = threadIdx.x;
  if (b < NB_EDGE) {
    int i = b * 256 + tid;                      // exactly covers 800000
    int d = dst[i];
    int pos = atomicAdd(&cnt[d], 1);
    if (pos < 64) csr[(d << 6) + pos] = src[i];
  } else if (b < NB_EDGE + NB_W) {
    int i = (b - NB_EDGE) * 256 + tid;          // exactly covers 90112
    const float* s;
    int base, local, msize;
    if (i < 16384)      { s = W1a; base = 0;      local = i;          msize = 16384; }
    else if (i < 32768) { s = W1b; base = 32768;  local = i - 16384;  msize = 16384; }
    else if (i < 49152) { s = W2a; base = 65536;  local = i - 32768;  msize = 16384; }
    else if (i < 65536) { s = W2b; base = 98304;  local = i - 49152;  msize = 16384; }
    else if (i < 81920) { s = W3a; base = 131072; local = i - 65536;  msize = 16384; }
    else                { s = W3b; base = 163840; local = i - 81920;  msize = 8192;  }
    float f = s[local];
    unsigned short hi = bf16_rne(f);
    float fh = __uint_as_float((unsigned)hi << 16);
    pool[base + local] = hi;
    pool[base + msize + local] = bf16_rne(f - fh);
  } else {
    int i = (b - NB_EDGE - NB_W) * 1024 + tid * 4;  // exactly covers 6,400,000
    float4 v = *reinterpret_cast<const float4*>(feat + i);
    ushort4 h;
    h.x = __half_as_ushort(__float2half_rn(v.x));
    h.y = __half_as_ushort(__float2half_rn(v.y));
    h.z = __half_as_ushort(__float2half_rn(v.z));
    h.w = __half_as_ushort(__float2half_rn(v.w));
    *reinterpret_cast<ushort4*>((unsigned short*)t16 + i) = h;
  }
}

// ---------------- aggregation: out[v] = self[v] + inv_deg * sum t16[src]  (fp32 out) ----------------
// one wave per node, lane covers 2 feature cols (fp16 pair), unroll 4 edges
template <bool SELF32>
__global__ __launch_bounds__(256)
void agg_kernel(const __half* __restrict__ t16, const float* __restrict__ xself,
                const int* __restrict__ csr, const int* __restrict__ cnt,
                float* __restrict__ out) {
  int node = blockIdx.x * 4 + (threadIdx.x >> 6);
  if (node >= N_NODES) return;
  const int lane = threadIdx.x & 63;
  int deg = cnt[node];
  int dloop = min(deg, 64);
  int beg = node << 6;
  float inv = 1.0f / fmaxf((float)deg, 1.0f);

  float s0 = 0.f, s1 = 0.f, t0 = 0.f, t1 = 0.f;
  float u0 = 0.f, u1 = 0.f, v0 = 0.f, v1 = 0.f;
  int e = 0;
  for (; e + 3 < dloop; e += 4) {
    int i0 = csr[beg + e], i1 = csr[beg + e + 1], i2 = csr[beg + e + 2], i3 = csr[beg + e + 3];
    float2 a = __half22float2(*reinterpret_cast<const __half2*>(t16 + (size_t)i0 * 128 + lane * 2));
    float2 b = __half22float2(*reinterpret_cast<const __half2*>(t16 + (size_t)i1 * 128 + lane * 2));
    float2 c = __half22float2(*reinterpret_cast<const __half2*>(t16 + (size_t)i2 * 128 + lane * 2));
    float2 d = __half22float2(*reinterpret_cast<const __half2*>(t16 + (size_t)i3 * 128 + lane * 2));
    s0 += a.x; s1 += a.y; t0 += b.x; t1 += b.y;
    u0 += c.x; u1 += c.y; v0 += d.x; v1 += d.y;
  }
  for (; e < dloop; ++e) {
    int i0 = csr[beg + e];
    float2 a = __half22float2(*reinterpret_cast<const __half2*>(t16 + (size_t)i0 * 128 + lane * 2));
    s0 += a.x; s1 += a.y;
  }
  float2 sm = make_float2(s0 + t0 + u0 + v0, s1 + t1 + u1 + v1);
  float2 xv;
  if (SELF32) {
    xv = *reinterpret_cast<const float2*>(xself + (size_t)node * 128 + lane * 2);
  } else {
    xv = __half22float2(*reinterpret_cast<const __half2*>(t16 + (size_t)node * 128 + lane * 2));
  }
  float2 o = make_float2(fmaf(sm.x, inv, xv.x), fmaf(sm.y, inv, xv.y));
  *reinterpret_cast<float2*>(out + (size_t)node * 128 + lane * 2) = o;
}

// ---------------- GEMM building blocks (split-bf16 MFMA) ----------------
__device__ __forceinline__ void stage_x(const float* __restrict__ X, int m0, int tid,
                                        char* ahi, char* alo, int M) {
  #pragma unroll
  for (int it = 0; it < 8; ++it) {
    int f = tid + it * 256;
    int row = f >> 5, c = f & 31;
    float4 v = make_float4(0.f, 0.f, 0.f, 0.f);
    if (m0 + row < M)
      v = *reinterpret_cast<const float4*>(X + (size_t)(m0 + row) * 128 + c * 4);
    ushort4 hi, lo;
    float fh;
    hi.x = bf16_rne(v.x); fh = __uint_as_float((unsigned)hi.x << 16); lo.x = bf16_rne(v.x - fh);
    hi.y = bf16_rne(v.y); fh = __uint_as_float((unsigned)hi.y << 16); lo.y = bf16_rne(v.y - fh);
    hi.z = bf16_rne(v.z); fh = __uint_as_float((unsigned)hi.z << 16); lo.z = bf16_rne(v.z - fh);
    hi.w = bf16_rne(v.w); fh = __uint_as_float((unsigned)hi.w << 16); lo.w = bf16_rne(v.w - fh);
    int bo = swz(row, c * 8);
    *reinterpret_cast<ushort4*>(ahi + bo) = hi;
    *reinterpret_cast<ushort4*>(alo + bo) = lo;
  }
}

template <int NB>
__device__ __forceinline__ void load_bfrag(const unsigned short* __restrict__ Wh,
                                           const unsigned short* __restrict__ Wl,
                                           int w, int lrow, int lg,
                                           bf16x8 (&bh)[NB][4], bf16x8 (&bl)[NB][4]) {
  #pragma unroll
  for (int nb = 0; nb < NB; ++nb) {
    int col = w * (16 * NB) + nb * 16 + lrow;
    #pragma unroll
    for (int kk = 0; kk < 4; ++kk) {
      int idx = col * 128 + kk * 32 + lg * 8;
      bh[nb][kk] = *reinterpret_cast<const bf16x8*>(Wh + idx);
      bl[nb][kk] = *reinterpret_cast<const bf16x8*>(Wl + idx);
    }
  }
}

template <int NB>
__device__ __forceinline__ void gemm_lds(const char* ahi, const char* alo, int lrow, int lg,
                                         const bf16x8 (&bh)[NB][4], const bf16x8 (&bl)[NB][4],
                                         f32x4 (&acc)[4][NB]) {
  #pragma unroll
  for (int i = 0; i < 4; ++i)
    #pragma unroll
    for (int nb = 0; nb < NB; ++nb) acc[i][nb] = (f32x4){0.f, 0.f, 0.f, 0.f};
  #pragma unroll
  for (int i = 0; i < 4; ++i) {
    #pragma unroll
    for (int kk = 0; kk < 4; ++kk) {
      int bo = swz(i * 16 + lrow, kk * 64 + lg * 16);
      bf16x8 ah = *reinterpret_cast<const bf16x8*>(ahi + bo);
      bf16x8 al = *reinterpret_cast<const bf16x8*>(alo + bo);
      #pragma unroll
      for (int nb = 0; nb < NB; ++nb) {
        acc[i][nb] = __builtin_amdgcn_mfma_f32_16x16x32_bf16(ah, bh[nb][kk], acc[i][nb], 0, 0, 0);
        acc[i][nb] = __builtin_amdgcn_mfma_f32_16x16x32_bf16(al, bh[nb][kk], acc[i][nb], 0, 0, 0);
        acc[i][nb] = __builtin_amdgcn_mfma_f32_16x16x32_bf16(ah, bl[nb][kk], acc[i][nb], 0, 0, 0);
      }
    }
  }
}

// h = relu(acc + bias) -> LDS bf16 hi/lo (128 cols, NB=2)
__device__ __forceinline__ void store_h(char* ahi, char* alo, const float* __restrict__ bias,
                                        int w, int lrow, int lg, f32x4 (&acc)[4][2]) {
  #pragma unroll
  for (int i = 0; i < 4; ++i) {
    #pragma unroll
    for (int nb = 0; nb < 2; ++nb) {
      int col = w * 32 + nb * 16 + lrow;
      float b = bias[col];
      #pragma unroll
      for (int r = 0; r < 4; ++r) {
        float v = fmaxf(acc[i][nb][r] + b, 0.f);
        int row = i * 16 + lg * 4 + r;
        unsigned short h = bf16_rne(v);
        float fh = __uint_as_float((unsigned)h << 16);
        unsigned short l2 = bf16_rne(v - fh);
        int bo = swz(row, col * 2);
        *reinterpret_cast<unsigned short*>(ahi + bo) = h;
        *reinterpret_cast<unsigned short*>(alo + bo) = l2;
      }
    }
  }
}

// ---------------- mlp1: bufA -> relu(relu(X W1a^T+b1a) W1b^T + b1b) -> fp16 table ----------------
__global__ __launch_bounds__(256)
void mlp1_kernel(const float* __restrict__ X, const unsigned short* __restrict__ p,
                 const float* __restrict__ b1a, const float* __restrict__ b1b,
                 __half* __restrict__ Y, int M) {
  __shared__ unsigned short Ahi[64 * 128];
  __shared__ unsigned short Alo[64 * 128];
  char* ahi = (char*)Ahi;
  char* alo = (char*)Alo;
  const int tid = threadIdx.x;
  const int w = tid >> 6, l = tid & 63;
  const int lrow = l & 15, lg = l >> 4;
  const int m0 = blockIdx.x * 64;

  stage_x(X, m0, tid, ahi, alo, M);
  __syncthreads();

  f32x4 acc[4][2];
  {
    bf16x8 bh[2][4], bl[2][4];
    load_bfrag<2>(p + 0, p + 16384, w, lrow, lg, bh, bl);       // W1a
    gemm_lds<2>(ahi, alo, lrow, lg, bh, bl, acc);
  }
  __syncthreads();
  {
    bf16x8 bh[2][4], bl[2][4];
    load_bfrag<2>(p + 32768, p + 49152, w, lrow, lg, bh, bl);   // W1b
    store_h(ahi, alo, b1a, w, lrow, lg, acc);
    __syncthreads();
    gemm_lds<2>(ahi, alo, lrow, lg, bh, bl, acc);
  }
  // epilogue: relu, write fp16
  #pragma unroll
  for (int i = 0; i < 4; ++i) {
    #pragma unroll
    for (int nb = 0; nb < 2; ++nb) {
      int col = w * 32 + nb * 16 + lrow;
      float b = b1b[col];
      #pragma unroll
      for (int r = 0; r < 4; ++r) {
        float v = fmaxf(acc[i][nb][r] + b, 0.f);
        int row = m0 + i * 16 + lg * 4 + r;
        if (row < M) Y[(size_t)row * 128 + col] = __float2half_rn(v);
      }
    }
  }
}

// ---------------- mlp2+head: bufA -> layer2 MLP -> head (4 GEMMs) -> d_out ----------------
__global__ __launch_bounds__(256)
void mlp2head_kernel(const float* __restrict__ X, const unsigned short* __restrict__ p,
                     const float* __restrict__ b2a, const float* __restrict__ b2b,
                     const float* __restrict__ b3a, const float* __restrict__ b3b,
                     float* __restrict__ Y, int M) {
  __shared__ unsigned short Ahi[64 * 128];
  __shared__ unsigned short Alo[64 * 128];
  char* ahi = (char*)Ahi;
  char* alo = (char*)Alo;
  const int tid = threadIdx.x;
  const int w = tid >> 6, l = tid & 63;
  const int lrow = l & 15, lg = l >> 4;
  const int m0 = blockIdx.x * 64;

  stage_x(X, m0, tid, ahi, alo, M);
  __syncthreads();

  f32x4 acc[4][2];
  {
    bf16x8 bh[2][4], bl[2][4];
    load_bfrag<2>(p + 65536, p + 81920, w, lrow, lg, bh, bl);   // W2a
    gemm_lds<2>(ahi, alo, lrow, lg, bh, bl, acc);
  }
  __syncthreads();
  {
    bf16x8 bh[2][4], bl[2][4];
    load_bfrag<2>(p + 98304, p + 114688, w, lrow, lg, bh, bl);  // W2b
    store_h(ahi, alo, b2a, w, lrow, lg, acc);
    __syncthreads();
    gemm_lds<2>(ahi, alo, lrow, lg, bh, bl, acc);
  }
  __syncthreads();
  {
    bf16x8 bh[2][4], bl[2][4];
    load_bfrag<2>(p + 131072, p + 147456, w, lrow, lg, bh, bl); // W3a
    store_h(ahi, alo, b2b, w, lrow, lg, acc);                   // layer-2 outer relu
    __syncthreads();
    gemm_lds<2>(ahi, alo, lrow, lg, bh, bl, acc);
  }
  __syncthreads();
  f32x4 acc1[4][1];
  {
    bf16x8 bh[1][4], bl[1][4];
    load_bfrag<1>(p + 163840, p + 172032, w, lrow, lg, bh, bl); // W3b
    store_h(ahi, alo, b3a, w, lrow, lg, acc);                   // head inner relu
    __syncthreads();
    gemm_lds<1>(ahi, alo, lrow, lg, bh, bl, acc1);
  }
  // epilogue: no relu, 64 cols
  #pragma unroll
  for (int i = 0; i < 4; ++i) {
    int col = w * 16 + lrow;
    float b = b3b[col];
    #pragma unroll
    for (int r = 0; r < 4; ++r) {
      float v = acc1[i][0][r] + b;
      int row = m0 + i * 16 + lg * 4 + r;
      if (row < M) Y[(size_t)row * 64 + col] = v;
    }
  }
}

// ---------------- launch ----------------
extern "C" void kernel_launch(void* const* d_in, const int* in_sizes, int n_in,
                              void* d_out, int out_size, void* d_ws, size_t ws_size,
                              hipStream_t stream) {
  const float* feat = (const float*)d_in[0];
  const int*   esrc = (const int*)d_in[1];
  const int*   edst = (const int*)d_in[2];
  const float* W1a = (const float*)d_in[3];  const float* b1a = (const float*)d_in[4];
  const float* W1b = (const float*)d_in[5];  const float* b1b = (const float*)d_in[6];
  const float* W2a = (const float*)d_in[7];  const float* b2a = (const float*)d_in[8];
  const float* W2b = (const float*)d_in[9];  const float* b2b = (const float*)d_in[10];
  const float* W3a = (const float*)d_in[11]; const float* b3a = (const float*)d_in[12];
  const float* W3b = (const float*)d_in[13]; const float* b3b = (const float*)d_in[14];

  char* ws = (char*)d_ws;
  float*  bufA = (float*)(ws + OFF_BUFA);
  __half* t16  = (__half*)(ws + OFF_T16);
  int*    cnt  = (int*)(ws + OFF_CNT);
  unsigned short* p = (unsigned short*)(ws + OFF_W);
  int*    csr  = (int*)(ws + OFF_CSR);

  hipMemsetAsync(cnt, 0, 200000, stream);

  prep_kernel<<<NB_EDGE + NB_W + NB_FEAT, 256, 0, stream>>>(
      esrc, edst, cnt, csr, W1a, W1b, W2a, W2b, W3a, W3b, p, feat, t16);

  const int AB = (N_NODES + 3) / 4;    // 12500
  const int GB = (N_NODES + 63) / 64;  // 782

  // layer 1: agg(feat via fp16 table, self fp32) -> bufA; mlp1 -> t16 (fp16)
  agg_kernel<true><<<AB, 256, 0, stream>>>(t16, feat, csr, cnt, bufA);
  mlp1_kernel<<<GB, 256, 0, stream>>>(bufA, p, b1a, b1b, t16, N_NODES);

  // layer 2 + head: agg(t16) -> bufA; mlp2+head -> d_out
  agg_kernel<false><<<AB, 256, 0, stream>>>(t16, feat, csr, cnt, bufA);
  mlp2head_kernel<<<GB, 256, 0, stream>>>(bufA, p, b2a, b2b, b3a, b3b,
                                          (float*)d_out, N_NODES);
}